// Round 3
// baseline (459.115 us; speedup 1.0000x reference)
//
#include <hip/hip_runtime.h>
#include <math.h>

static constexpr int Bn    = 8192;
static constexpr int Kn    = 400;
static constexpr int Sn    = 20;                 // sections per batch
static constexpr int NROWS = Bn * Kn;            // 3,276,800 CE rows
static constexpr int NGRP  = Bn * Sn;            // 163,840 Procrustes groups

// CE: 2560 blocks x 1280 rows (5 chunks of 256 rows, LDS-transposed, single buffer)
static constexpr int CE_BLOCKS = 2560;
static constexpr int CE_ROWS_PER_BLOCK = 1280;
// PR: 2560 blocks x 64 groups, block-cooperative LDS staging
static constexpr int PR_BLOCKS = 2560;
static constexpr int FUSED_BLOCKS = CE_BLOCKS + PR_BLOCKS;   // 5120, 1:1 interleave

// ws layout (floats): all slots written unconditionally each call.
static constexpr int WS_CE   = 0;      // [2560]
static constexpr int WS_KP   = 4096;   // [2560]
static constexpr int WS_ROT  = 8192;   // [2560]
static constexpr int WS_CENT = 12288;  // [2560]

__device__ __forceinline__ float smooth_l1f(float x) {
    float ax = fabsf(x);
    return ax < 1.0f ? 0.5f * x * x : ax - 0.5f;
}

// ---------------- Fused CE + Procrustes ----------------
// Shared LDS union: CE uses 5120 floats (20,480 B) as a wave-private transpose
// buffer; proc uses 7680 floats (30,720 B) as a block-staged P+G tile.
// Union = 30,720 B -> 5 blocks/CU (20 waves/CU), up from 4.
__global__ __launch_bounds__(256) void fused_kernel(
    const float* __restrict__ logits,
    const int*   __restrict__ labels,
    const float* __restrict__ P,
    const float* __restrict__ G,
    float*       __restrict__ ws)
{
    const int t   = threadIdx.x;
    const int bid = blockIdx.x;
    const int lane = t & 63, wid = t >> 6;
    __shared__ __align__(16) float lds[7680];   // 30,720 B union buffer
    __shared__ float sm[4];

    if ((bid & 1) == 0) {
        // ---------------- CE path ----------------
        // Single 20,480 B buffer. Per-wave LDS ops are in-order, and the
        // compiler cannot prove the row-reads and slice-writes disjoint
        // (same array), so chunk c's ds_reads always precede chunk c+1's
        // ds_writes -> wave-private, barrier-free, no vmcnt(0) drains.
        const int cb = bid >> 1;                           // 0..2559
        const size_t blockRow0 = (size_t)cb * CE_ROWS_PER_BLOCK;
        const float* __restrict__ gsrc = logits + blockRow0 * 20;

        float4 pf[5];
        auto load_chunk = [&](int c) {
            const float* p = gsrc + (size_t)c * 5120 + wid * 1280 + lane * 4;
#pragma unroll
            for (int i = 0; i < 5; i++)
                pf[i] = *reinterpret_cast<const float4*>(p + i * 256);
        };
        auto store_chunk = [&]() {
#pragma unroll
            for (int i = 0; i < 5; i++)
                *reinterpret_cast<float4*>(&lds[wid * 1280 + i * 256 + lane * 4]) = pf[i];
        };

        load_chunk(0);
        store_chunk();

        float acc = 0.0f;
#pragma unroll
        for (int c = 0; c < 5; c++) {
            if (c + 1 < 5) load_chunk(c + 1);              // issue next-chunk loads early

            const float4* rowp = reinterpret_cast<const float4*>(&lds[t * 20]);
            float x[20];
#pragma unroll
            for (int i = 0; i < 5; i++) {
                float4 v = rowp[i];
                x[4*i+0] = v.x; x[4*i+1] = v.y; x[4*i+2] = v.z; x[4*i+3] = v.w;
            }
            int lab = labels[blockRow0 + c * 256 + t];      // lane-contiguous
            float m = x[0];
#pragma unroll
            for (int j = 1; j < 20; j++) m = fmaxf(m, x[j]);
            float se = 0.0f, xl = 0.0f;
#pragma unroll
            for (int j = 0; j < 20; j++) {
                se += __expf(x[j] - m);
                xl = (j == lab) ? x[j] : xl;
            }
            acc += __logf(se) + m - xl;

            if (c + 1 < 5) store_chunk();                  // vmcnt wait lands here, after compute
        }

#pragma unroll
        for (int o = 32; o > 0; o >>= 1) acc += __shfl_down(acc, o);
        if (lane == 0) sm[wid] = acc;
        __syncthreads();
        if (t == 0) ws[WS_CE + cb] = sm[0] + sm[1] + sm[2] + sm[3];
        return;
    }

    // ---------------- Procrustes path ----------------
    // Block owns 64 groups = 3840 floats of P + 3840 of G.
    // Stage both coalesced (dword, lane-contiguous) into LDS; then wave 0
    // processes one group per lane entirely from LDS (pass C included:
    // zero global re-read). Waves 1-3 exit after staging; co-resident CE
    // blocks keep the CU busy during the short compute phase.
    const int pb = bid >> 1;                               // 0..2559
    const size_t g0 = (size_t)pb * 64;
    const float* __restrict__ Pg = P + g0 * 60;
    const float* __restrict__ Gg = G + g0 * 60;

    float vP[15], vG[15];
#pragma unroll
    for (int i = 0; i < 15; i++) { vP[i] = Pg[t + 256*i]; vG[i] = Gg[t + 256*i]; }
#pragma unroll
    for (int i = 0; i < 15; i++) {
        lds[       t + 256*i] = vP[i];
        lds[3840 + t + 256*i] = vG[i];
    }
    __syncthreads();
    if (t >= 64) return;

    const float4* __restrict__ pr = reinterpret_cast<const float4*>(&lds[t * 60]);
    const float4* __restrict__ gr = reinterpret_cast<const float4*>(&lds[3840 + t * 60]);

    // Pass A (fused): keypoint smooth-L1 + coordinate sums + raw product matrix.
    // H = sum Gc Pc^T = sum G P^T - 20 * mg mp^T
    float kp = 0.0f;
    float sp0=0,sp1=0,sp2=0, sg0=0,sg1=0,sg2=0;
    float S00=0,S01=0,S02=0, S10=0,S11=0,S12=0, S20=0,S21=0,S22=0;
#pragma unroll
    for (int ch = 0; ch < 5; ch++) {
        float4 a0 = pr[3*ch+0], a1 = pr[3*ch+1], a2 = pr[3*ch+2];
        float4 b0 = gr[3*ch+0], b1 = gr[3*ch+1], b2 = gr[3*ch+2];
        float pv[12] = {a0.x,a0.y,a0.z,a0.w, a1.x,a1.y,a1.z,a1.w, a2.x,a2.y,a2.z,a2.w};
        float gv[12] = {b0.x,b0.y,b0.z,b0.w, b1.x,b1.y,b1.z,b1.w, b2.x,b2.y,b2.z,b2.w};
#pragma unroll
        for (int q = 0; q < 4; q++) {
            float p0 = pv[3*q+0], p1 = pv[3*q+1], p2 = pv[3*q+2];
            float g0v = gv[3*q+0], g1v = gv[3*q+1], g2v = gv[3*q+2];
            kp += smooth_l1f(p0-g0v) + smooth_l1f(p1-g1v) + smooth_l1f(p2-g2v);
            sp0 += p0; sp1 += p1; sp2 += p2;
            sg0 += g0v; sg1 += g1v; sg2 += g2v;
            S00 += g0v*p0; S01 += g0v*p1; S02 += g0v*p2;
            S10 += g1v*p0; S11 += g1v*p1; S12 += g1v*p2;
            S20 += g2v*p0; S21 += g2v*p1; S22 += g2v*p2;
        }
    }
    const float inv20 = 1.0f / 20.0f;
    float mp[3] = {sp0*inv20, sp1*inv20, sp2*inv20};
    float mg[3] = {sg0*inv20, sg1*inv20, sg2*inv20};
    float cent = smooth_l1f(mp[0]-mg[0]) + smooth_l1f(mp[1]-mg[1]) + smooth_l1f(mp[2]-mg[2]);

    float X[3][3];
    X[0][0] = S00 - 20.0f*mg[0]*mp[0];  X[0][1] = S01 - 20.0f*mg[0]*mp[1];  X[0][2] = S02 - 20.0f*mg[0]*mp[2];
    X[1][0] = S10 - 20.0f*mg[1]*mp[0];  X[1][1] = S11 - 20.0f*mg[1]*mp[1];  X[1][2] = S12 - 20.0f*mg[1]*mp[2];
    X[2][0] = S20 - 20.0f*mg[2]*mp[0];  X[2][1] = S21 - 20.0f*mg[2]*mp[1];  X[2][2] = S22 - 20.0f*mg[2]*mp[2];

    // Polar factor R = U Vh via det-scaled Newton
#pragma unroll
    for (int it = 0; it < 8; it++) {
        float c00 =  X[1][1]*X[2][2] - X[1][2]*X[2][1];
        float c01 = -(X[1][0]*X[2][2] - X[1][2]*X[2][0]);
        float c02 =  X[1][0]*X[2][1] - X[1][1]*X[2][0];
        float c10 = -(X[0][1]*X[2][2] - X[0][2]*X[2][1]);
        float c11 =  X[0][0]*X[2][2] - X[0][2]*X[2][0];
        float c12 = -(X[0][0]*X[2][1] - X[0][1]*X[2][0]);
        float c20 =  X[0][1]*X[1][2] - X[0][2]*X[1][1];
        float c21 = -(X[0][0]*X[1][2] - X[0][2]*X[1][0]);
        float c22 =  X[0][0]*X[1][1] - X[0][1]*X[1][0];
        float d = X[0][0]*c00 + X[0][1]*c01 + X[0][2]*c02;
        float ad = fmaxf(fabsf(d), 1e-30f);
        float gam = __powf(ad, -(1.0f/3.0f));
        float dsn = (d < 0.0f) ? -ad : ad;
        float k1 = 0.5f * gam;
        float k2 = 0.5f / (gam * dsn);
        X[0][0] = k1*X[0][0] + k2*c00;  X[0][1] = k1*X[0][1] + k2*c01;  X[0][2] = k1*X[0][2] + k2*c02;
        X[1][0] = k1*X[1][0] + k2*c10;  X[1][1] = k1*X[1][1] + k2*c11;  X[1][2] = k1*X[1][2] + k2*c12;
        X[2][0] = k1*X[2][0] + k2*c20;  X[2][1] = k1*X[2][1] + k2*c21;  X[2][2] = k1*X[2][2] + k2*c22;
    }
    float s9 = X[0][0]+X[0][1]+X[0][2]+X[1][0]+X[1][1]+X[1][2]+X[2][0]+X[2][1]+X[2][2];
    if (!(s9 == s9) || fabsf(s9) > 1e10f) {
        X[0][0]=1; X[0][1]=0; X[0][2]=0;
        X[1][0]=0; X[1][1]=1; X[1][2]=0;
        X[2][0]=0; X[2][1]=0; X[2][2]=1;
    }

    // Pass C: rot = sum smooth_l1( Pc @ R - Gc ), re-read from LDS (no global)
    float rot = 0.0f;
#pragma unroll
    for (int ch = 0; ch < 5; ch++) {
        float4 a0 = pr[3*ch+0], a1 = pr[3*ch+1], a2 = pr[3*ch+2];
        float4 b0 = gr[3*ch+0], b1 = gr[3*ch+1], b2 = gr[3*ch+2];
        float pv[12] = {a0.x,a0.y,a0.z,a0.w, a1.x,a1.y,a1.z,a1.w, a2.x,a2.y,a2.z,a2.w};
        float gv[12] = {b0.x,b0.y,b0.z,b0.w, b1.x,b1.y,b1.z,b1.w, b2.x,b2.y,b2.z,b2.w};
#pragma unroll
        for (int q = 0; q < 4; q++) {
            float pc0 = pv[3*q+0]-mp[0], pc1 = pv[3*q+1]-mp[1], pc2 = pv[3*q+2]-mp[2];
            float gc0 = gv[3*q+0]-mg[0], gc1 = gv[3*q+1]-mg[1], gc2 = gv[3*q+2]-mg[2];
            float a0r = pc0*X[0][0] + pc1*X[1][0] + pc2*X[2][0] - gc0;
            float a1r = pc0*X[0][1] + pc1*X[1][1] + pc2*X[2][1] - gc1;
            float a2r = pc0*X[0][2] + pc1*X[1][2] + pc2*X[2][2] - gc2;
            rot += smooth_l1f(a0r) + smooth_l1f(a1r) + smooth_l1f(a2r);
        }
    }

    // wave 0 reduce (t == lane here), one partial per block
#pragma unroll
    for (int o = 32; o > 0; o >>= 1) {
        kp   += __shfl_down(kp, o);
        rot  += __shfl_down(rot, o);
        cent += __shfl_down(cent, o);
    }
    if (t == 0) {
        ws[WS_KP   + pb] = kp;
        ws[WS_ROT  + pb] = rot;
        ws[WS_CENT + pb] = cent;
    }
}

// ---------------- Final reduction of per-block partials ----------------
__global__ __launch_bounds__(256) void reduce_kernel(
    const float* __restrict__ ws, float* __restrict__ out)
{
    const int t = threadIdx.x;
    float s_ce = 0, s_kp = 0, s_rot = 0, s_cent = 0;
    for (int i = t; i < CE_BLOCKS; i += 256) s_ce += ws[WS_CE + i];
    for (int i = t; i < PR_BLOCKS; i += 256) {
        s_kp   += ws[WS_KP + i];
        s_rot  += ws[WS_ROT + i];
        s_cent += ws[WS_CENT + i];
    }
#pragma unroll
    for (int o = 32; o > 0; o >>= 1) {
        s_ce   += __shfl_down(s_ce, o);
        s_kp   += __shfl_down(s_kp, o);
        s_rot  += __shfl_down(s_rot, o);
        s_cent += __shfl_down(s_cent, o);
    }
    __shared__ float sm[4][4];
    int lane = t & 63, wid = t >> 6;
    if (lane == 0) { sm[0][wid]=s_ce; sm[1][wid]=s_kp; sm[2][wid]=s_rot; sm[3][wid]=s_cent; }
    __syncthreads();
    if (t == 0) {
        float ce   = (sm[0][0]+sm[0][1]+sm[0][2]+sm[0][3]) * (1.0f / (float)NROWS);
        float kp   = (sm[1][0]+sm[1][1]+sm[1][2]+sm[1][3]) * (1.0f / (float)(NROWS * 3));
        float rot  = (sm[2][0]+sm[2][1]+sm[2][2]+sm[2][3]) * (1.0f / (float)(NROWS * 3));
        float cent = (sm[3][0]+sm[3][1]+sm[3][2]+sm[3][3]) * (1.0f / (float)(NGRP * 3));
        out[0] = ce + 4.0f * kp + 5.0f * rot + 6.0f * cent;
    }
}

extern "C" void kernel_launch(void* const* d_in, const int* in_sizes, int n_in,
                              void* d_out, int out_size, void* d_ws, size_t ws_size,
                              hipStream_t stream) {
    const float* pred_kp = (const float*)d_in[0];
    const float* gt_kp   = (const float*)d_in[1];
    const float* logits  = (const float*)d_in[2];
    const int*   labels  = (const int*)d_in[3];
    float* out = (float*)d_out;
    float* ws  = (float*)d_ws;

    fused_kernel<<<FUSED_BLOCKS, 256, 0, stream>>>(logits, labels, pred_kp, gt_kp, ws);
    reduce_kernel<<<1, 256, 0, stream>>>(ws, out);
}

// Round 4
// 406.607 us; speedup vs baseline: 1.1291x; 1.1291x over previous
//
#include <hip/hip_runtime.h>
#include <math.h>

static constexpr int Bn    = 8192;
static constexpr int Kn    = 400;
static constexpr int Sn    = 20;                 // sections per batch
static constexpr int NROWS = Bn * Kn;            // 3,276,800 CE rows
static constexpr int NGRP  = Bn * Sn;            // 163,840 Procrustes groups

// CE: 2560 blocks x 1280 rows (5 chunks of 256 rows, LDS-transposed, double-buffered)
static constexpr int CE_BLOCKS = 2560;
static constexpr int CE_ROWS_PER_BLOCK = 1280;
static constexpr int PR_BLOCKS = 640,  PR_TPB = 256;              // 640*256 = NGRP
static constexpr int FUSED_BLOCKS = CE_BLOCKS + PR_BLOCKS;        // 3200, 4:1 interleave

// ws layout (floats): all slots written unconditionally each call.
static constexpr int WS_CE   = 0;      // [2560]
static constexpr int WS_KP   = 4096;   // [640]
static constexpr int WS_ROT  = 8192;   // [640]
static constexpr int WS_CENT = 12288;  // [640]

typedef float f4 __attribute__((ext_vector_type(4)));

__device__ __forceinline__ float smooth_l1f(float x) {
    float ax = fabsf(x);
    return ax < 1.0f ? 0.5f * x * x : ax - 0.5f;
}

// ---------------- Fused CE + Procrustes ----------------
// CE reads are strictly read-once -> non-temporal loads (no L2/L3 allocation).
// Mechanism: the harness's 1 GB workspace poison fill leaves L2/L3 full of
// dirty lines; normally-allocating reads must evict them to HBM first
// (observed as 61 MB WRITE_SIZE on a kernel storing 40 KB). NT loads skip
// allocation entirely. P/G keep normal caching (pass C re-reads hit L2).
// LDS is exactly 40,960 B (cross-wave scratch folded into lbuf) -> 4 blocks/CU.
__global__ __launch_bounds__(256) void fused_kernel(
    const float* __restrict__ logits,
    const int*   __restrict__ labels,
    const float* __restrict__ P,
    const float* __restrict__ G,
    float*       __restrict__ ws)
{
    const int t   = threadIdx.x;
    const int bid = blockIdx.x;
    const int lane = t & 63, wid = t >> 6;
    __shared__ __align__(16) float lbuf[2][5120];   // 40,960 B total, no extra scratch

    if ((bid % 5) != 4) {
        // ---------------- CE path ----------------
        const int cb = (bid / 5) * 4 + (bid % 5);          // 0..2559
        const size_t blockRow0 = (size_t)cb * CE_ROWS_PER_BLOCK;
        const float* __restrict__ gsrc = logits + blockRow0 * 20;

        // prefetch all 5 chunk labels up front (read-once -> nt)
        int labv[5];
#pragma unroll
        for (int c = 0; c < 5; c++)
            labv[c] = __builtin_nontemporal_load(labels + blockRow0 + c * 256 + t);

        f4 pf[5];
        auto load_chunk = [&](int c) {
            const float* p = gsrc + (size_t)c * 5120 + wid * 1280 + lane * 4;
#pragma unroll
            for (int i = 0; i < 5; i++)
                pf[i] = __builtin_nontemporal_load(reinterpret_cast<const f4*>(p + i * 256));
        };
        auto store_chunk = [&](int buf) {
#pragma unroll
            for (int i = 0; i < 5; i++)
                *reinterpret_cast<f4*>(&lbuf[buf][wid * 1280 + i * 256 + lane * 4]) = pf[i];
        };

        load_chunk(0);
        store_chunk(0);

        float acc = 0.0f;
#pragma unroll
        for (int c = 0; c < 5; c++) {
            if (c + 1 < 5) load_chunk(c + 1);              // issue next-chunk loads early

            // read own row from LDS (bytes t*80, 16B-aligned; wave-private region)
            const f4* rowp = reinterpret_cast<const f4*>(&lbuf[c & 1][t * 20]);
            float x[20];
#pragma unroll
            for (int i = 0; i < 5; i++) {
                f4 v = rowp[i];
                x[4*i+0] = v.x; x[4*i+1] = v.y; x[4*i+2] = v.z; x[4*i+3] = v.w;
            }
            // label logit: one LDS read instead of 20 cndmasks
            float xl = lbuf[c & 1][t * 20 + labv[c]];

            // tree max: depth 5 instead of 19
            float mx[10];
#pragma unroll
            for (int j = 0; j < 10; j++) mx[j] = fmaxf(x[2*j], x[2*j+1]);
#pragma unroll
            for (int j = 0; j < 5; j++) mx[j] = fmaxf(mx[2*j], mx[2*j+1]);
            float m = fmaxf(fmaxf(mx[0], mx[1]), fmaxf(mx[2], fmaxf(mx[3], mx[4])));

            // 4-way partial exp sums: depth ~7 instead of 19
            float se0 = 0, se1 = 0, se2 = 0, se3 = 0;
#pragma unroll
            for (int j = 0; j < 20; j += 4) {
                se0 += __expf(x[j+0] - m);
                se1 += __expf(x[j+1] - m);
                se2 += __expf(x[j+2] - m);
                se3 += __expf(x[j+3] - m);
            }
            float se = (se0 + se1) + (se2 + se3);
            acc += __logf(se) + m - xl;

            if (c + 1 < 5) store_chunk((c + 1) & 1);       // vmcnt wait lands here, after compute
        }

#pragma unroll
        for (int o = 32; o > 0; o >>= 1) acc += __shfl_down(acc, o);
        __syncthreads();                                    // all lbuf row-reads done
        if (lane == 0) lbuf[0][wid] = acc;
        __syncthreads();
        if (t == 0) ws[WS_CE + cb] = lbuf[0][0] + lbuf[0][1] + lbuf[0][2] + lbuf[0][3];
        return;
    }

    // ---------------- Procrustes path (round-2 proven structure) ----------------
    const int pb  = bid / 5;                               // 0..639
    const int grp = pb * PR_TPB + t;
    const float4* __restrict__ pp = reinterpret_cast<const float4*>(P) + (size_t)grp * 15;
    const float4* __restrict__ gg = reinterpret_cast<const float4*>(G) + (size_t)grp * 15;

    // Pass A (fused): keypoint smooth-L1 + coordinate sums + raw product matrix.
    // H = sum Gc Pc^T = sum G P^T - 20 * mg mp^T
    float kp = 0.0f;
    float sp0=0,sp1=0,sp2=0, sg0=0,sg1=0,sg2=0;
    float S00=0,S01=0,S02=0, S10=0,S11=0,S12=0, S20=0,S21=0,S22=0;
#pragma unroll
    for (int ch = 0; ch < 5; ch++) {
        float4 a0 = pp[3*ch+0], a1 = pp[3*ch+1], a2 = pp[3*ch+2];
        float4 b0 = gg[3*ch+0], b1 = gg[3*ch+1], b2 = gg[3*ch+2];
        float pv[12] = {a0.x,a0.y,a0.z,a0.w, a1.x,a1.y,a1.z,a1.w, a2.x,a2.y,a2.z,a2.w};
        float gv[12] = {b0.x,b0.y,b0.z,b0.w, b1.x,b1.y,b1.z,b1.w, b2.x,b2.y,b2.z,b2.w};
#pragma unroll
        for (int q = 0; q < 4; q++) {
            float p0 = pv[3*q+0], p1 = pv[3*q+1], p2 = pv[3*q+2];
            float g0v = gv[3*q+0], g1v = gv[3*q+1], g2v = gv[3*q+2];
            kp += smooth_l1f(p0-g0v) + smooth_l1f(p1-g1v) + smooth_l1f(p2-g2v);
            sp0 += p0; sp1 += p1; sp2 += p2;
            sg0 += g0v; sg1 += g1v; sg2 += g2v;
            S00 += g0v*p0; S01 += g0v*p1; S02 += g0v*p2;
            S10 += g1v*p0; S11 += g1v*p1; S12 += g1v*p2;
            S20 += g2v*p0; S21 += g2v*p1; S22 += g2v*p2;
        }
    }
    const float inv20 = 1.0f / 20.0f;
    float mp[3] = {sp0*inv20, sp1*inv20, sp2*inv20};
    float mg[3] = {sg0*inv20, sg1*inv20, sg2*inv20};
    float cent = smooth_l1f(mp[0]-mg[0]) + smooth_l1f(mp[1]-mg[1]) + smooth_l1f(mp[2]-mg[2]);

    float X[3][3];
    X[0][0] = S00 - 20.0f*mg[0]*mp[0];  X[0][1] = S01 - 20.0f*mg[0]*mp[1];  X[0][2] = S02 - 20.0f*mg[0]*mp[2];
    X[1][0] = S10 - 20.0f*mg[1]*mp[0];  X[1][1] = S11 - 20.0f*mg[1]*mp[1];  X[1][2] = S12 - 20.0f*mg[1]*mp[2];
    X[2][0] = S20 - 20.0f*mg[2]*mp[0];  X[2][1] = S21 - 20.0f*mg[2]*mp[1];  X[2][2] = S22 - 20.0f*mg[2]*mp[2];

    // Polar factor R = U Vh via det-scaled Newton
#pragma unroll
    for (int it = 0; it < 8; it++) {
        float c00 =  X[1][1]*X[2][2] - X[1][2]*X[2][1];
        float c01 = -(X[1][0]*X[2][2] - X[1][2]*X[2][0]);
        float c02 =  X[1][0]*X[2][1] - X[1][1]*X[2][0];
        float c10 = -(X[0][1]*X[2][2] - X[0][2]*X[2][1]);
        float c11 =  X[0][0]*X[2][2] - X[0][2]*X[2][0];
        float c12 = -(X[0][0]*X[2][1] - X[0][1]*X[2][0]);
        float c20 =  X[0][1]*X[1][2] - X[0][2]*X[1][1];
        float c21 = -(X[0][0]*X[1][2] - X[0][2]*X[1][0]);
        float c22 =  X[0][0]*X[1][1] - X[0][1]*X[1][0];
        float d = X[0][0]*c00 + X[0][1]*c01 + X[0][2]*c02;
        float ad = fmaxf(fabsf(d), 1e-30f);
        float gam = __powf(ad, -(1.0f/3.0f));
        float dsn = (d < 0.0f) ? -ad : ad;
        float k1 = 0.5f * gam;
        float k2 = 0.5f / (gam * dsn);
        X[0][0] = k1*X[0][0] + k2*c00;  X[0][1] = k1*X[0][1] + k2*c01;  X[0][2] = k1*X[0][2] + k2*c02;
        X[1][0] = k1*X[1][0] + k2*c10;  X[1][1] = k1*X[1][1] + k2*c11;  X[1][2] = k1*X[1][2] + k2*c12;
        X[2][0] = k1*X[2][0] + k2*c20;  X[2][1] = k1*X[2][1] + k2*c21;  X[2][2] = k1*X[2][2] + k2*c22;
    }
    float s9 = X[0][0]+X[0][1]+X[0][2]+X[1][0]+X[1][1]+X[1][2]+X[2][0]+X[2][1]+X[2][2];
    if (!(s9 == s9) || fabsf(s9) > 1e10f) {
        X[0][0]=1; X[0][1]=0; X[0][2]=0;
        X[1][0]=0; X[1][1]=1; X[1][2]=0;
        X[2][0]=0; X[2][1]=0; X[2][2]=1;
    }

    // Pass C: rot = sum smooth_l1( Pc @ R - Gc ), re-read (L2 hit: block's
    // 120 KB was warmed by pass A moments earlier)
    float rot = 0.0f;
#pragma unroll
    for (int ch = 0; ch < 5; ch++) {
        float4 a0 = pp[3*ch+0], a1 = pp[3*ch+1], a2 = pp[3*ch+2];
        float4 b0 = gg[3*ch+0], b1 = gg[3*ch+1], b2 = gg[3*ch+2];
        float pv[12] = {a0.x,a0.y,a0.z,a0.w, a1.x,a1.y,a1.z,a1.w, a2.x,a2.y,a2.z,a2.w};
        float gv[12] = {b0.x,b0.y,b0.z,b0.w, b1.x,b1.y,b1.z,b1.w, b2.x,b2.y,b2.z,b2.w};
#pragma unroll
        for (int q = 0; q < 4; q++) {
            float pc0 = pv[3*q+0]-mp[0], pc1 = pv[3*q+1]-mp[1], pc2 = pv[3*q+2]-mp[2];
            float gc0 = gv[3*q+0]-mg[0], gc1 = gv[3*q+1]-mg[1], gc2 = gv[3*q+2]-mg[2];
            float a0r = pc0*X[0][0] + pc1*X[1][0] + pc2*X[2][0] - gc0;
            float a1r = pc0*X[0][1] + pc1*X[1][1] + pc2*X[2][1] - gc1;
            float a2r = pc0*X[0][2] + pc1*X[1][2] + pc2*X[2][2] - gc2;
            rot += smooth_l1f(a0r) + smooth_l1f(a1r) + smooth_l1f(a2r);
        }
    }

    // block reduce (4 waves) via shfl, cross-wave scratch folded into lbuf
#pragma unroll
    for (int o = 32; o > 0; o >>= 1) {
        kp   += __shfl_down(kp, o);
        rot  += __shfl_down(rot, o);
        cent += __shfl_down(cent, o);
    }
    if (lane == 0) { lbuf[0][wid] = kp; lbuf[0][4+wid] = rot; lbuf[0][8+wid] = cent; }
    __syncthreads();
    if (t == 0) {
        ws[WS_KP   + pb] = lbuf[0][0] + lbuf[0][1] + lbuf[0][2]  + lbuf[0][3];
        ws[WS_ROT  + pb] = lbuf[0][4] + lbuf[0][5] + lbuf[0][6]  + lbuf[0][7];
        ws[WS_CENT + pb] = lbuf[0][8] + lbuf[0][9] + lbuf[0][10] + lbuf[0][11];
    }
}

// ---------------- Final reduction of per-block partials ----------------
__global__ __launch_bounds__(256) void reduce_kernel(
    const float* __restrict__ ws, float* __restrict__ out)
{
    const int t = threadIdx.x;
    float s_ce = 0, s_kp = 0, s_rot = 0, s_cent = 0;
    for (int i = t; i < CE_BLOCKS; i += 256) s_ce += ws[WS_CE + i];
    for (int i = t; i < PR_BLOCKS; i += 256) {
        s_kp   += ws[WS_KP + i];
        s_rot  += ws[WS_ROT + i];
        s_cent += ws[WS_CENT + i];
    }
#pragma unroll
    for (int o = 32; o > 0; o >>= 1) {
        s_ce   += __shfl_down(s_ce, o);
        s_kp   += __shfl_down(s_kp, o);
        s_rot  += __shfl_down(s_rot, o);
        s_cent += __shfl_down(s_cent, o);
    }
    __shared__ float sm[4][4];
    int lane = t & 63, wid = t >> 6;
    if (lane == 0) { sm[0][wid]=s_ce; sm[1][wid]=s_kp; sm[2][wid]=s_rot; sm[3][wid]=s_cent; }
    __syncthreads();
    if (t == 0) {
        float ce   = (sm[0][0]+sm[0][1]+sm[0][2]+sm[0][3]) * (1.0f / (float)NROWS);
        float kp   = (sm[1][0]+sm[1][1]+sm[1][2]+sm[1][3]) * (1.0f / (float)(NROWS * 3));
        float rot  = (sm[2][0]+sm[2][1]+sm[2][2]+sm[2][3]) * (1.0f / (float)(NROWS * 3));
        float cent = (sm[3][0]+sm[3][1]+sm[3][2]+sm[3][3]) * (1.0f / (float)(NGRP * 3));
        out[0] = ce + 4.0f * kp + 5.0f * rot + 6.0f * cent;
    }
}

extern "C" void kernel_launch(void* const* d_in, const int* in_sizes, int n_in,
                              void* d_out, int out_size, void* d_ws, size_t ws_size,
                              hipStream_t stream) {
    const float* pred_kp = (const float*)d_in[0];
    const float* gt_kp   = (const float*)d_in[1];
    const float* logits  = (const float*)d_in[2];
    const int*   labels  = (const int*)d_in[3];
    float* out = (float*)d_out;
    float* ws  = (float*)d_ws;

    fused_kernel<<<FUSED_BLOCKS, 256, 0, stream>>>(logits, labels, pred_kp, gt_kp, ws);
    reduce_kernel<<<1, 256, 0, stream>>>(ws, out);
}